// Round 1
// baseline (327.764 us; speedup 1.0000x reference)
//
#include <hip/hip_runtime.h>
#include <hip/hip_bf16.h>

typedef __bf16 bf16x8 __attribute__((ext_vector_type(8)));
typedef float  f32x4  __attribute__((ext_vector_type(4)));

#define LOG2E 1.4426950408889634f
#define LN2   0.6931471805599453f

__device__ __forceinline__ float rcp_(float x){
#if __has_builtin(__builtin_amdgcn_rcpf)
  return __builtin_amdgcn_rcpf(x);
#else
  return 1.0f / x;
#endif
}
__device__ __forceinline__ float sig_(float x){  // 1/(1+e^-x), saturates correctly at +-inf
  return rcp_(1.0f + exp2f(-LOG2E * x));
}
__device__ __forceinline__ float tanh_(float x){ // 1 - 2/(e^{2x}+1)
  return 1.0f - 2.0f * rcp_(1.0f + exp2f(2.0f * LOG2E * x));
}

struct LstmArgs {
  const float* Wih[4]; const float* Whh[4];
  const float* bih[4]; const float* bhh[4];
  const float* h0[4];  const float* c0[4];
};

// ---------------------------------------------------------------------------
// Kernel A: 4 directions x 64 batch-blocks of 32 rows. One block = one LSTM
// chain for 32 batch rows. Weights live in registers as MFMA B-fragments.
// LDS holds the A operand: [32 rows][168] bf16 = [h(128) | x_t(28) | pad].
// Gate tile G[32][512] = [h|x] @ Wcat^T + bias via mfma_f32_16x16x32_bf16.
// Wave w owns gate-N-tiles {2w,2w+1, 8+2w,8+2w+1, 16+2w,.., 24+2w,..} so each
// lane holds i/f/g/o of the same unit (col = l&15) -> lane-local c/h update.
// ---------------------------------------------------------------------------
__global__ __launch_bounds__(256, 1) void lstm4_kernel(const float* __restrict__ x,
                                                       LstmArgs args,
                                                       float* __restrict__ featT)
{
  const int dir = blockIdx.x >> 6;          // 0=lr_f 1=lr_b 2=ud_f 3=ud_b
  const int b0  = (blockIdx.x & 63) * 32;
  const int tid = threadIdx.x;
  const int w   = tid >> 6;                 // wave 0..3
  const int l   = tid & 63;
  const int lc  = l & 15;
  const int lr4 = l >> 4;

  const float* __restrict__ Wih = args.Wih[dir];
  const float* __restrict__ Whh = args.Whh[dir];
  const float* __restrict__ bih = args.bih[dir];
  const float* __restrict__ bhh = args.bhh[dir];
  const float* __restrict__ h0  = args.h0[dir];
  const float* __restrict__ c0  = args.c0[dir];
  const int rev  = dir & 1;                 // lr_b / ud_b scan reversed
  const int tmul = (dir < 2) ? 28 : 1;      // lr: x[b][t][j]   ud: x[b][j][t]
  const int jmul = (dir < 2) ? 1  : 28;

  __shared__ __align__(16) __bf16 hcat[32 * 168];   // 10.5 KiB

  // ---- B fragments (weights) into registers: 8 N-tiles x 5 K-steps --------
  bf16x8 bfr[8][5];
  float  bias[8];
#pragma unroll
  for (int tl = 0; tl < 8; ++tl){
    const int tg = 2*w + (tl & 1) + 8*(tl >> 1);   // global N-tile
    const int g  = tg*16 + lc;                     // gate row 0..511
    bias[tl] = bih[g] + bhh[g];
#pragma unroll
    for (int kk = 0; kk < 4; ++kk){                // h part, K = 0..127
      const float* p = Whh + g*128 + kk*32 + lr4*8;
      bf16x8 v;
#pragma unroll
      for (int j = 0; j < 8; ++j) v[j] = (__bf16)p[j];
      bfr[tl][kk] = v;
    }
    bf16x8 v;                                      // x part, K = 128..155 (+pad)
#pragma unroll
    for (int j = 0; j < 8; ++j){
      const int xi = lr4*8 + j;
      v[j] = (xi < 28) ? (__bf16)Wih[g*28 + xi] : (__bf16)0.0f;
    }
    bfr[tl][4] = v;
  }

  // ---- initial state: c in regs, h0 -> LDS (bf16) --------------------------
  float cst[2][2][4];
  float hfin[2][2][4];
#pragma unroll
  for (int m = 0; m < 2; ++m)
#pragma unroll
  for (int p = 0; p < 2; ++p)
#pragma unroll
  for (int r = 0; r < 4; ++r){
    const int row = 16*m + 4*lr4 + r;
    const int col = 32*w + 16*p + lc;
    cst[m][p][r] = c0[(b0+row)*128 + col];
    hcat[row*168 + col] = (__bf16)h0[(b0+row)*128 + col];
    hfin[m][p][r] = 0.0f;
  }
  if (tid < 32){
#pragma unroll
    for (int j = 0; j < 4; ++j) hcat[tid*168 + 156 + j] = (__bf16)0.0f;  // K pad
  }

  // ---- 28 sequential steps -------------------------------------------------
  for (int s = 0; s < 28; ++s){
    const int t = rev ? (27 - s) : s;
    // stage x_t into LDS cols 128..155
    for (int idx = tid; idx < 32*28; idx += 256){
      const int row = idx / 28;
      const int jj  = idx - row*28;
      hcat[row*168 + 128 + jj] = (__bf16)x[(b0+row)*784 + t*tmul + jj*jmul];
    }
    __syncthreads();   // h + x writes visible

    f32x4 acc[2][8];
#pragma unroll
    for (int m = 0; m < 2; ++m)
#pragma unroll
    for (int tl = 0; tl < 8; ++tl){
      f32x4 bv = {bias[tl], bias[tl], bias[tl], bias[tl]};
      acc[m][tl] = bv;
    }

#pragma unroll
    for (int m = 0; m < 2; ++m){
#pragma unroll
      for (int kk = 0; kk < 5; ++kk){
        const bf16x8 a = *(const bf16x8*)&hcat[(16*m + lc)*168 + kk*32 + lr4*8];
#pragma unroll
        for (int tl = 0; tl < 8; ++tl)
          acc[m][tl] = __builtin_amdgcn_mfma_f32_16x16x32_bf16(a, bfr[tl][kk], acc[m][tl], 0, 0, 0);
      }
    }
    __syncthreads();   // all A-frag reads done before h rewrite

    // gates: elementwise, lane-local
#pragma unroll
    for (int m = 0; m < 2; ++m)
#pragma unroll
    for (int p = 0; p < 2; ++p)
#pragma unroll
    for (int r = 0; r < 4; ++r){
      const float iv = acc[m][0+p][r];
      const float fv = acc[m][2+p][r];
      const float gv = acc[m][4+p][r];
      const float ov = acc[m][6+p][r];
      const float cc = sig_(fv)*cst[m][p][r] + sig_(iv)*tanh_(gv);
      cst[m][p][r] = cc;
      const float hv = sig_(ov)*tanh_(cc);
      hfin[m][p][r] = hv;
      const int row = 16*m + 4*lr4 + r;
      const int col = 32*w + 16*p + lc;
      hcat[row*168 + col] = (__bf16)hv;
    }
  }

  // ---- final h -> featT[512][2048] (seq-major for the fc LSTM) -------------
#pragma unroll
  for (int m = 0; m < 2; ++m)
#pragma unroll
  for (int p = 0; p < 2; ++p){
    const int col = 32*w + 16*p + lc;
    f32x4 v = {hfin[m][p][0], hfin[m][p][1], hfin[m][p][2], hfin[m][p][3]};
    *(f32x4*)&featT[(dir*128 + col)*2048 + b0 + 16*m + 4*lr4] = v;
  }
}

// ---------------------------------------------------------------------------
// Kernel B: fc LSTM over T=512, HF=10, then log-softmax.
// 16 lanes per batch element; lane k<10 owns hidden unit k (h,c in regs,
// Whh rows k,10+k,20+k,30+k in 40 regs). Per step: broadcast 10 h values via
// __shfl inside the 16-lane group, 40 FMAs, fast sigmoid/tanh.
// ---------------------------------------------------------------------------
__global__ __launch_bounds__(256) void fc_lstm_kernel(const float* __restrict__ featT,
                                                      const float* __restrict__ Wih,
                                                      const float* __restrict__ Whh,
                                                      const float* __restrict__ bih,
                                                      const float* __restrict__ bhh,
                                                      const float* __restrict__ h0,
                                                      const float* __restrict__ c0,
                                                      float* __restrict__ out)
{
  const int tid = threadIdx.x;
  const int k   = tid & 15;
  const int b   = blockIdx.x * 16 + (tid >> 4);
  const int kc  = (k < 10) ? k : 9;       // clamp idle lanes' addressing
  const int gbase = tid & 48;             // group base lane within the wave

  float wi[10], wf[10], wg[10], wo[10];
#pragma unroll
  for (int m = 0; m < 10; ++m){
    wi[m] = Whh[( 0 + kc)*10 + m];
    wf[m] = Whh[(10 + kc)*10 + m];
    wg[m] = Whh[(20 + kc)*10 + m];
    wo[m] = Whh[(30 + kc)*10 + m];
  }
  const float xwi = Wih[kc],      xwf = Wih[10+kc];
  const float xwg = Wih[20+kc],   xwo = Wih[30+kc];
  const float bi  = bih[kc]    + bhh[kc];
  const float bf_ = bih[10+kc] + bhh[10+kc];
  const float bg  = bih[20+kc] + bhh[20+kc];
  const float bo  = bih[30+kc] + bhh[30+kc];

  float h = (k < 10) ? h0[b*10 + k] : 0.0f;
  float c = (k < 10) ? c0[b*10 + k] : 0.0f;

  float xt_next = featT[b];
  for (int t = 0; t < 512; ++t){
    const float xt = xt_next;
    if (t < 511) xt_next = featT[(t+1)*2048 + b];
    float ai = bi  + xwi*xt;
    float af = bf_ + xwf*xt;
    float ag = bg  + xwg*xt;
    float ao = bo  + xwo*xt;
#pragma unroll
    for (int m = 0; m < 10; ++m){
      const float hm = __shfl(h, gbase + m, 64);
      ai += wi[m]*hm; af += wf[m]*hm; ag += wg[m]*hm; ao += wo[m]*hm;
    }
    c = sig_(af)*c + sig_(ai)*tanh_(ag);
    h = sig_(ao)*tanh_(c);
  }

  // log-softmax across the 10 units of this group
  float hv = (k < 10) ? h : -3.0e38f;
  float mx = hv;
#pragma unroll
  for (int d = 1; d < 16; d <<= 1) mx = fmaxf(mx, __shfl_xor(mx, d, 64));
  float e = (k < 10) ? exp2f(LOG2E * (h - mx)) : 0.0f;
  float se = e;
#pragma unroll
  for (int d = 1; d < 16; d <<= 1) se += __shfl_xor(se, d, 64);
  const float ls = h - mx - LN2 * log2f(se);
  if (k < 10) out[b*10 + k] = ls;
}

extern "C" void kernel_launch(void* const* d_in, const int* in_sizes, int n_in,
                              void* d_out, int out_size, void* d_ws, size_t ws_size,
                              hipStream_t stream)
{
  const float* x = (const float*)d_in[0];
  LstmArgs a;
  const int base[4] = {1, 5, 9, 13};   // lr_f, lr_b, ud_f, ud_b
  for (int d = 0; d < 4; ++d){
    a.Wih[d] = (const float*)d_in[base[d] + 0];
    a.Whh[d] = (const float*)d_in[base[d] + 1];
    a.bih[d] = (const float*)d_in[base[d] + 2];
    a.bhh[d] = (const float*)d_in[base[d] + 3];
  }
  const float* h0lr = (const float*)d_in[21];
  const float* c0lr = (const float*)d_in[22];
  const float* h0ud = (const float*)d_in[23];
  const float* c0ud = (const float*)d_in[24];
  a.h0[0] = h0lr;               a.c0[0] = c0lr;
  a.h0[1] = h0lr + 2048*128;    a.c0[1] = c0lr + 2048*128;
  a.h0[2] = h0ud;               a.c0[2] = c0ud;
  a.h0[3] = h0ud + 2048*128;    a.c0[3] = c0ud + 2048*128;

  float* featT = (float*)d_ws;   // [512][2048] f32 = 4 MiB

  lstm4_kernel<<<256, 256, 0, stream>>>(x, a, featT);
  fc_lstm_kernel<<<128, 256, 0, stream>>>(featT,
      (const float*)d_in[17], (const float*)d_in[18],
      (const float*)d_in[19], (const float*)d_in[20],
      (const float*)d_in[25], (const float*)d_in[26],
      (float*)d_out);
}

// Round 2
// 237.888 us; speedup vs baseline: 1.3778x; 1.3778x over previous
//
#include <hip/hip_runtime.h>
#include <hip/hip_bf16.h>

typedef __bf16 bf16x8 __attribute__((ext_vector_type(8)));
typedef float  f32x4  __attribute__((ext_vector_type(4)));
typedef float  f32x2  __attribute__((ext_vector_type(2)));

#define LOG2E 1.4426950408889634f
#define LN2   0.6931471805599453f

__device__ __forceinline__ float rcp_(float x){
#if __has_builtin(__builtin_amdgcn_rcpf)
  return __builtin_amdgcn_rcpf(x);
#else
  return 1.0f / x;
#endif
}
__device__ __forceinline__ float ex2_(float x){
#if __has_builtin(__builtin_amdgcn_exp2f)
  return __builtin_amdgcn_exp2f(x);
#else
  return exp2f(x);
#endif
}
__device__ __forceinline__ float lg2_(float x){
#if __has_builtin(__builtin_amdgcn_logf)
  return __builtin_amdgcn_logf(x);
#else
  return log2f(x);
#endif
}
// pre-scaled activations: inputs already multiplied by -LOG2E (sigmoid) / 2*LOG2E (tanh)
__device__ __forceinline__ float sigp_(float xp){ return rcp_(1.0f + ex2_(xp)); }        // sigmoid(x), xp=-LOG2E*x
__device__ __forceinline__ float tanp_(float gp){ return 1.0f - 2.0f*rcp_(1.0f + ex2_(gp)); } // tanh(g), gp=2*LOG2E*g

struct LstmArgs {
  const float* Wih[4]; const float* Whh[4];
  const float* bih[4]; const float* bhh[4];
  const float* h0[4];  const float* c0[4];
};

// ---------------------------------------------------------------------------
// Kernel A: 4 directions x 64 batch-blocks of 32 rows. Weights in registers as
// MFMA B-fragments (pre-scaled by the activation log2e factors). The block's
// whole x-tile is staged into LDS ONCE (xstage[28][32][40] bf16, transposed
// for ud dirs) so the 28-step serial loop touches no global memory.
// ---------------------------------------------------------------------------
__global__ __launch_bounds__(256, 1) void lstm4_kernel(const float* __restrict__ x,
                                                       LstmArgs args,
                                                       float* __restrict__ featT)
{
  const int dir = blockIdx.x >> 6;          // 0=lr_f 1=lr_b 2=ud_f 3=ud_b
  const int b0  = (blockIdx.x & 63) * 32;
  const int tid = threadIdx.x;
  const int w   = tid >> 6;                 // wave 0..3
  const int l   = tid & 63;
  const int lc  = l & 15;
  const int lr4 = l >> 4;

  const float* __restrict__ Wih = args.Wih[dir];
  const float* __restrict__ Whh = args.Whh[dir];
  const float* __restrict__ bih = args.bih[dir];
  const float* __restrict__ bhh = args.bhh[dir];
  const float* __restrict__ h0  = args.h0[dir];
  const float* __restrict__ c0  = args.c0[dir];
  const int rev = dir & 1;
  const bool lrdir = (dir < 2);

  __shared__ __align__(16) __bf16 hcat[32 * 168];        // 10.5 KiB (cols 0..127 used)
  __shared__ __align__(16) __bf16 xstage[28 * 32 * 40];  // 70 KiB, rows 80B (16B-aligned)

  // ---- B fragments (weights) into registers, pre-scaled --------------------
  // tile->gate type: tl>>1 = 0:i 1:f 2:g 3:o ; scale g rows by 2*LOG2E, rest by -LOG2E
  bf16x8 bfr[8][5];
  float  bias[8];
#pragma unroll
  for (int tl = 0; tl < 8; ++tl){
    const int tg = 2*w + (tl & 1) + 8*(tl >> 1);
    const int g  = tg*16 + lc;
    const float sc = ((tl >> 1) == 2) ? 2.0f*LOG2E : -LOG2E;
    bias[tl] = (bih[g] + bhh[g]) * sc;
#pragma unroll
    for (int kk = 0; kk < 4; ++kk){
      const float* p = Whh + g*128 + kk*32 + lr4*8;
      bf16x8 v;
#pragma unroll
      for (int j = 0; j < 8; ++j) v[j] = (__bf16)(p[j] * sc);
      bfr[tl][kk] = v;
    }
    bf16x8 v;
#pragma unroll
    for (int j = 0; j < 8; ++j){
      const int xi = lr4*8 + j;
      v[j] = (xi < 28) ? (__bf16)(Wih[g*28 + xi] * sc) : (__bf16)0.0f;
    }
    bfr[tl][4] = v;
  }

  // ---- stage the whole x tile once (transpose for ud) ----------------------
  for (int idx = tid; idx < 32*784; idx += 256){
    const int row = idx / 784;
    const int q   = idx - row*784;
    int t, j;
    if (lrdir){ t = q / 28; j = q - t*28; }
    else      { j = q / 28; t = q - j*28; }
    xstage[(t*32 + row)*40 + j] = (__bf16)x[(b0+row)*784 + q];
  }
  for (int idx = tid; idx < 28*32; idx += 256){
    const int t = idx >> 5, row = idx & 31;
    __bf16* p = &xstage[(t*32 + row)*40 + 28];
    p[0] = p[1] = p[2] = p[3] = (__bf16)0.0f;
  }

  // ---- initial state -------------------------------------------------------
  float cst[2][2][4];
  float hfin[2][2][4];
#pragma unroll
  for (int m = 0; m < 2; ++m)
#pragma unroll
  for (int p = 0; p < 2; ++p)
#pragma unroll
  for (int r = 0; r < 4; ++r){
    const int row = 16*m + 4*lr4 + r;
    const int col = 32*w + 16*p + lc;
    cst[m][p][r] = c0[(b0+row)*128 + col];
    hcat[row*168 + col] = (__bf16)h0[(b0+row)*128 + col];
    hfin[m][p][r] = 0.0f;
  }

  // ---- 28 sequential steps (no global traffic inside) ----------------------
  for (int s = 0; s < 28; ++s){
    const int t = rev ? (27 - s) : s;
    __syncthreads();   // h (and initial h0/xstage) writes visible

    f32x4 acc[2][8];
#pragma unroll
    for (int m = 0; m < 2; ++m)
#pragma unroll
    for (int tl = 0; tl < 8; ++tl){
      f32x4 bv = {bias[tl], bias[tl], bias[tl], bias[tl]};
      acc[m][tl] = bv;
    }

#pragma unroll
    for (int m = 0; m < 2; ++m){
#pragma unroll
      for (int kk = 0; kk < 5; ++kk){
        const bf16x8 a = (kk < 4)
          ? *(const bf16x8*)&hcat[(16*m + lc)*168 + kk*32 + lr4*8]
          : *(const bf16x8*)&xstage[(t*32 + 16*m + lc)*40 + lr4*8];
#pragma unroll
        for (int tl = 0; tl < 8; ++tl)
          acc[m][tl] = __builtin_amdgcn_mfma_f32_16x16x32_bf16(a, bfr[tl][kk], acc[m][tl], 0, 0, 0);
      }
    }
    __syncthreads();   // all A-frag reads done before h rewrite

#pragma unroll
    for (int m = 0; m < 2; ++m)
#pragma unroll
    for (int p = 0; p < 2; ++p)
#pragma unroll
    for (int r = 0; r < 4; ++r){
      const float iv = acc[m][0+p][r];   // pre-scaled by -LOG2E
      const float fv = acc[m][2+p][r];   // pre-scaled by -LOG2E
      const float gv = acc[m][4+p][r];   // pre-scaled by 2*LOG2E
      const float ov = acc[m][6+p][r];   // pre-scaled by -LOG2E
      const float cc = sigp_(fv)*cst[m][p][r] + sigp_(iv)*tanp_(gv);
      cst[m][p][r] = cc;
      const float hv = sigp_(ov)*tanp_(2.0f*LOG2E*cc);
      hfin[m][p][r] = hv;
      const int row = 16*m + 4*lr4 + r;
      const int col = 32*w + 16*p + lc;
      hcat[row*168 + col] = (__bf16)hv;
    }
  }

  // ---- final h -> featT[512][2048] ----------------------------------------
#pragma unroll
  for (int m = 0; m < 2; ++m)
#pragma unroll
  for (int p = 0; p < 2; ++p){
    const int col = 32*w + 16*p + lc;
    f32x4 v = {hfin[m][p][0], hfin[m][p][1], hfin[m][p][2], hfin[m][p][3]};
    *(f32x4*)&featT[(dir*128 + col)*2048 + b0 + 16*m + 4*lr4] = v;
  }
}

// ---------------------------------------------------------------------------
// Kernel B: fc LSTM (T=512, HF=10) + log-softmax. 16 lanes per batch element,
// TWO elements per lane-group (f32x2 state) for ILP; h broadcast via
// single-op ds_swizzle (src = (lane&0x10)|m), all 20 issued before use.
// Weights pre-scaled by the activation log2e factors.
// ---------------------------------------------------------------------------
__global__ __launch_bounds__(256) void fc_lstm_kernel(const float* __restrict__ featT,
                                                      const float* __restrict__ Wih,
                                                      const float* __restrict__ Whh,
                                                      const float* __restrict__ bih,
                                                      const float* __restrict__ bhh,
                                                      const float* __restrict__ h0,
                                                      const float* __restrict__ c0,
                                                      float* __restrict__ out)
{
  const int tid = threadIdx.x;
  const int k   = tid & 15;
  const int b   = blockIdx.x * 32 + ((tid >> 4) << 1);   // elements b, b+1
  const int kc  = (k < 10) ? k : 9;

  const float sI = -LOG2E, sG = 2.0f*LOG2E;
  float wi[10], wf[10], wg[10], wo[10];
#pragma unroll
  for (int m = 0; m < 10; ++m){
    wi[m] = Whh[( 0 + kc)*10 + m] * sI;
    wf[m] = Whh[(10 + kc)*10 + m] * sI;
    wg[m] = Whh[(20 + kc)*10 + m] * sG;
    wo[m] = Whh[(30 + kc)*10 + m] * sI;
  }
  const float xwi = Wih[kc]*sI,    xwf = Wih[10+kc]*sI;
  const float xwg = Wih[20+kc]*sG, xwo = Wih[30+kc]*sI;
  const float bi  = (bih[kc]    + bhh[kc])    * sI;
  const float bf_ = (bih[10+kc] + bhh[10+kc]) * sI;
  const float bg  = (bih[20+kc] + bhh[20+kc]) * sG;
  const float bo  = (bih[30+kc] + bhh[30+kc]) * sI;

  f32x2 h, c;
  h.x = (k < 10) ? h0[b*10 + k]     : 0.0f;
  h.y = (k < 10) ? h0[(b+1)*10 + k] : 0.0f;
  c.x = (k < 10) ? c0[b*10 + k]     : 0.0f;
  c.y = (k < 10) ? c0[(b+1)*10 + k] : 0.0f;

  f32x2 xt_next = *(const f32x2*)&featT[b];
  for (int t = 0; t < 512; ++t){
    const f32x2 xt = xt_next;
    if (t < 511) xt_next = *(const f32x2*)&featT[(t+1)*2048 + b];

    f32x2 hm[10];
#define BC(M) \
    hm[M].x = __int_as_float(__builtin_amdgcn_ds_swizzle(__float_as_int(h.x), ((M)<<5)|0x10)); \
    hm[M].y = __int_as_float(__builtin_amdgcn_ds_swizzle(__float_as_int(h.y), ((M)<<5)|0x10));
    BC(0) BC(1) BC(2) BC(3) BC(4) BC(5) BC(6) BC(7) BC(8) BC(9)
#undef BC

    f32x2 ai = bi  + xwi*xt;
    f32x2 af = bf_ + xwf*xt;
    f32x2 ag = bg  + xwg*xt;
    f32x2 ao = bo  + xwo*xt;
#pragma unroll
    for (int m = 0; m < 10; ++m){
      ai += wi[m]*hm[m]; af += wf[m]*hm[m];
      ag += wg[m]*hm[m]; ao += wo[m]*hm[m];
    }
    f32x2 si, sf, so, tg;
    si.x = sigp_(ai.x); si.y = sigp_(ai.y);
    sf.x = sigp_(af.x); sf.y = sigp_(af.y);
    so.x = sigp_(ao.x); so.y = sigp_(ao.y);
    tg.x = tanp_(ag.x); tg.y = tanp_(ag.y);
    c = sf*c + si*tg;
    f32x2 tc;
    tc.x = tanp_(sG*c.x); tc.y = tanp_(sG*c.y);
    h = so*tc;
  }

  // log-softmax over the 10 units of each element
  const float hv2[2] = {h.x, h.y};
#pragma unroll
  for (int e = 0; e < 2; ++e){
    const float hval = hv2[e];
    float mx = (k < 10) ? hval : -3.0e38f;
#pragma unroll
    for (int d = 1; d < 16; d <<= 1) mx = fmaxf(mx, __shfl_xor(mx, d, 64));
    const float ev = (k < 10) ? ex2_(LOG2E*(hval - mx)) : 0.0f;
    float se = ev;
#pragma unroll
    for (int d = 1; d < 16; d <<= 1) se += __shfl_xor(se, d, 64);
    const float ls = hval - mx - LN2*lg2_(se);
    if (k < 10) out[(b+e)*10 + k] = ls;
  }
}

extern "C" void kernel_launch(void* const* d_in, const int* in_sizes, int n_in,
                              void* d_out, int out_size, void* d_ws, size_t ws_size,
                              hipStream_t stream)
{
  const float* x = (const float*)d_in[0];
  LstmArgs a;
  const int base[4] = {1, 5, 9, 13};   // lr_f, lr_b, ud_f, ud_b
  for (int d = 0; d < 4; ++d){
    a.Wih[d] = (const float*)d_in[base[d] + 0];
    a.Whh[d] = (const float*)d_in[base[d] + 1];
    a.bih[d] = (const float*)d_in[base[d] + 2];
    a.bhh[d] = (const float*)d_in[base[d] + 3];
  }
  const float* h0lr = (const float*)d_in[21];
  const float* c0lr = (const float*)d_in[22];
  const float* h0ud = (const float*)d_in[23];
  const float* c0ud = (const float*)d_in[24];
  a.h0[0] = h0lr;               a.c0[0] = c0lr;
  a.h0[1] = h0lr + 2048*128;    a.c0[1] = c0lr + 2048*128;
  a.h0[2] = h0ud;               a.c0[2] = c0ud;
  a.h0[3] = h0ud + 2048*128;    a.c0[3] = c0ud + 2048*128;

  float* featT = (float*)d_ws;   // [512][2048] f32 = 4 MiB

  lstm4_kernel<<<256, 256, 0, stream>>>(x, a, featT);
  fc_lstm_kernel<<<64, 256, 0, stream>>>(featT,
      (const float*)d_in[17], (const float*)d_in[18],
      (const float*)d_in[19], (const float*)d_in[20],
      (const float*)d_in[25], (const float*)d_in[26],
      (float*)d_out);
}